// Round 15
// baseline (201.390 us; speedup 1.0000x reference)
//
#include <hip/hip_runtime.h>
#include <hip/hip_bf16.h>

typedef unsigned int  uint;
typedef unsigned short ushort;
typedef short bf16x8 __attribute__((ext_vector_type(8)));
typedef float f32x4  __attribute__((ext_vector_type(4)));

#define HW   4096
#define KD   2304   // 9 taps * 256 c

__device__ __forceinline__ void load_lds16(const void* g, void* l) {
    __builtin_amdgcn_global_load_lds((const __attribute__((address_space(1))) void*)g,
                                     (__attribute__((address_space(3))) void*)l, 16, 0, 0);
}
__device__ __forceinline__ float blo(uint u) { return __uint_as_float(u << 16); }
__device__ __forceinline__ float bhi(uint u) { return __uint_as_float(u & 0xffff0000u); }
__device__ __forceinline__ uint pack2(float e, float o) {
    __hip_bfloat16 he = __float2bfloat16(e), ho = __float2bfloat16(o);
    return (uint)(*(ushort*)&he) | ((uint)(*(ushort*)&ho) << 16);
}

// ---- merged prep: x->x2t transpose | w_def->bt | w_off->bt0 | stats zero ----
__global__ __launch_bounds__(256) void prep_all(const float* __restrict__ x,
                                                const float* __restrict__ w_def,
                                                const float* __restrict__ w_off,
                                                uint* __restrict__ x2t,
                                                ushort* __restrict__ bt,
                                                ushort* __restrict__ bt0,
                                                float* __restrict__ stats) {
    __shared__ uint tl[32][65];
    int bid = blockIdx.x;
    int t = threadIdx.x;
    if (bid < 1024) {
        int ab  = bid & 63;
        int cpb = (bid >> 6) & 3;
        int b   = bid >> 8;
#pragma unroll
        for (int i = 0; i < 8; ++i) {
            int idx = i * 256 + t;
            int cp = idx >> 6, a = idx & 63;
            const float* p = x + ((size_t)(b * 256 + (cpb * 32 + cp) * 2)) * HW + ab * 64 + a;
            tl[cp][a] = pack2(p[0], p[HW]);
        }
        __syncthreads();
#pragma unroll
        for (int i = 0; i < 8; ++i) {
            int idx = i * 256 + t;
            int a = idx >> 5, cp = idx & 31;
            x2t[((size_t)b * 4096 + ab * 64 + a) * 128 + cpb * 32 + cp] = tl[cp][a];
        }
    } else if (bid < 3328) {
        int idx = (bid - 1024) * 256 + t;          // 589,824
        int c   = idx & 255;
        int tap = (idx >> 8) % 9;
        int o   = idx / KD;
        __hip_bfloat16 h = __float2bfloat16(w_def[(o * 256 + c) * 9 + tap]);
        bt[idx] = *(ushort*)&h;
    } else if (bid < 3616) {
        int idx = (bid - 3328) * 256 + t;          // 73,728
        int c   = idx & 255;
        int tap = (idx >> 8) % 9;
        int j   = idx / KD;
        float v = (j < 18) ? w_off[(j * 256 + c) * 9 + tap] : 0.f;
        __hip_bfloat16 h = __float2bfloat16(v);
        bt0[idx] = *(ushort*)&h;
    } else {
        float4 z = {0.f, 0.f, 0.f, 0.f};
        ((float4*)stats)[t] = z;                   // 256 float4 = 4096 B
    }
}

// ---- MEGA kernel, N-SPLIT (R14) with waves_per_eu(8,8): allows 32 waves/CU
// = 2 blocks/CU. R14 proved (4,4) capped residency at 1 block (Occupancy 39%).
// VGPR measured 52 <= 64 budget at 8 waves/EU -> no spill. LDS 66K*2 <= 160K.
__global__ __attribute__((amdgpu_waves_per_eu(8, 8))) __launch_bounds__(1024)
void fused_main(const uint* __restrict__ x2t,
                const ushort* __restrict__ bt,
                const ushort* __restrict__ bt0,
                const float* __restrict__ b_off,
                float* __restrict__ out,
                float* __restrict__ stats) {
    int id = blockIdx.x;                      // 512 blocks
    int nh = id & 1;                          // N-half: channels nh*128..+127
    int bid2 = id >> 1;                       // 0..255 (b,h) tile
    int xcd = bid2 & 7;
    int b = xcd >> 1, h = (xcd & 1) * 32 + (bid2 >> 3);
    int t = threadIdx.x;
    int wv = t >> 6, lane = t & 63;
    int mrow = lane & 15, quad = lane >> 4;
    bool producer = (wv < 8);
    int ppos = ((wv & 7) << 3) + (lane >> 3); // producer position 0..63
    int pc8  = lane & 7;                      // producer 16B chunk (4 cp)
    int wvc  = wv - 8;                        // consumer wave 0..7

    __shared__ __align__(16) char smem[66048];
    uint*   lX   = (uint*)smem;               // phase A: 24576 B
    ushort* lB0  = (ushort*)(smem + 24576);   // phase A: 36864 B
    float*  sOff = (float*)(smem + 61440);    // 18*64*4 = 4608 B
    int*    sAc  = (int*)smem;                // main: 9216 B
    float*  sWc  = (float*)(smem + 9216);     // 9216 B
    ushort* lA   = (ushort*)(smem + 18432);   // 4 * 8192 B

    // ================= phase A: offset conv (duplicated per pair) =================
    {
        f32x4 accO = {0.f, 0.f, 0.f, 0.f};
        int mq = wv & 3, nn = (wv >> 2) & 1;
        for (int cb = 0; cb < 4; ++cb) {
#pragma unroll
            for (int s = 0; s < 2; ++s) {             // 24 lX phases / 16 waves
                int q = s * 16 + wv;
                if (q < 24) {
                    int dy  = q >> 3;
                    int y   = h + dy - 1;
                    int sub = q & 7;
                    int wl  = sub * 8 + (lane >> 3);
                    int cps = ((lane & 7) ^ ((lane >> 3) & 7)) * 4;
                    if ((unsigned)y < 64u) {
                        const uint* src = x2t + ((size_t)(b * 4096 + y * 64 + wl)) * 128 + cb * 32 + cps;
                        load_lds16(src, &lX[q * 256]);
                    } else {
                        uint4 z = {0u, 0u, 0u, 0u};
                        *(uint4*)&lX[q * 256 + lane * 4] = z;
                    }
                }
            }
#pragma unroll
            for (int s = 0; s < 3; ++s) {             // 36 lB0 phases / 16 waves
                int q = s * 16 + wv;
                if (q < 36) {
                    int e = q * 512 + lane * 8;
                    int o  = e / 576;
                    int r  = e - o * 576;
                    int chp = r >> 3;
                    int ch  = chp ^ (o & 7);
                    int tap = ch >> 3, k8 = ch & 7;
                    const ushort* src = bt0 + (size_t)o * KD + tap * 256 + cb * 64 + k8 * 8;
                    load_lds16(src, &lB0[q * 512]);
                }
            }
            __syncthreads();
            if (producer) {
#pragma unroll
                for (int tap = 0; tap < 9; ++tap) {
                    int dy = tap / 3, dx = tap % 3;
                    int xx = mq * 16 + mrow + dx - 1;
                    bool vx = (unsigned)xx < 64u;
                    int xc = min(max(xx, 0), 63);
#pragma unroll
                    for (int kb = 0; kb < 2; ++kb) {
                        int cp0 = kb * 16 + quad * 4;
                        uint4 ad = {0u, 0u, 0u, 0u};
                        if (vx) ad = *(const uint4*)&lX[dy * 2048 + xc * 32 + (cp0 ^ ((xc & 7) * 4))];
                        bf16x8 af = *(bf16x8*)&ad;
                        int o = nn * 16 + mrow;
                        int chs = (tap * 8 + (((kb * 4 + quad)) ^ (o & 7)));
                        bf16x8 bfr = *(const bf16x8*)&lB0[o * 576 + chs * 8];
                        accO = __builtin_amdgcn_mfma_f32_16x16x32_bf16(af, bfr, accO, 0, 0, 0);
                    }
                }
            }
            __syncthreads();
        }
        if (producer) {
            int o = ((wv >> 2) & 1) * 16 + mrow;
            if (o < 18) {
                float bias = b_off[o];
                int wpos = (wv & 3) * 16 + quad * 4;
                sOff[o * 64 + wpos + 0] = accO.x + bias;
                sOff[o * 64 + wpos + 1] = accO.y + bias;
                sOff[o * 64 + wpos + 2] = accO.z + bias;
                sOff[o * 64 + wpos + 3] = accO.w + bias;
            }
        }
        __syncthreads();
    }

    // ================= coord phase =================
    for (int i = t; i < 576; i += 1024) {
        int tap = i >> 6, ww = i & 63;
        float oy = sOff[(2 * tap) * 64 + ww];
        float ox = sOff[(2 * tap + 1) * 64 + ww];
        float py = oy + (float)(tap / 3 + h - 1);
        float px = ox + (float)(tap % 3 + ww - 1);
        float y0f = floorf(py), x0f = floorf(px);
        float wy1 = py - y0f, wx1 = px - x0f;
        float wy0 = 1.f - wy1, wx0 = 1.f - wx1;
        bool vy0 = (y0f >= 0.f) && (y0f <= 63.f);
        bool vy1 = (y0f >= -1.f) && (y0f <= 62.f);
        bool vx0 = (x0f >= 0.f) && (x0f <= 63.f);
        bool vx1 = (x0f >= -1.f) && (x0f <= 62.f);
        int iy0 = min(max((int)y0f, 0), 63),  iy1 = min(max((int)y0f + 1, 0), 63);
        int ix0 = min(max((int)x0f, 0), 63),  ix1 = min(max((int)x0f + 1, 0), 63);
        sAc[0 * 576 + tap * 64 + ww] = iy0 * 64 + ix0;
        sAc[1 * 576 + tap * 64 + ww] = iy0 * 64 + ix1;
        sAc[2 * 576 + tap * 64 + ww] = iy1 * 64 + ix0;
        sAc[3 * 576 + tap * 64 + ww] = iy1 * 64 + ix1;
        sWc[0 * 576 + tap * 64 + ww] = wy0 * wx0 * (float)(vy0 && vx0);
        sWc[1 * 576 + tap * 64 + ww] = wy0 * wx1 * (float)(vy0 && vx1);
        sWc[2 * 576 + tap * 64 + ww] = wy1 * wx0 * (float)(vy1 && vx0);
        sWc[3 * 576 + tap * 64 + ww] = wy1 * wx1 * (float)(vy1 && vx1);
    }
    __syncthreads();

    // ================= main P/C loop (N-halved consumers) =================
    f32x4 acc[4];
#pragma unroll
    for (int m = 0; m < 4; ++m) acc[m] = {0.f, 0.f, 0.f, 0.f};

    const uint* xb = x2t + (size_t)b * 4096 * 128;

    auto issue_gathers = [&](int sl, uint4 (&g)[4]) {
        int tap = sl >> 2, cb = sl & 3;
        const uint* xp = xb + cb * 32 + pc8 * 4;
        g[0] = *(const uint4*)(xp + (size_t)sAc[0 * 576 + tap * 64 + ppos] * 128);
        g[1] = *(const uint4*)(xp + (size_t)sAc[1 * 576 + tap * 64 + ppos] * 128);
        g[2] = *(const uint4*)(xp + (size_t)sAc[2 * 576 + tap * 64 + ppos] * 128);
        g[3] = *(const uint4*)(xp + (size_t)sAc[3 * 576 + tap * 64 + ppos] * 128);
    };
    auto finish = [&](int sl, ushort* lAb, const uint4 (&g)[4]) {
        int tap = sl >> 2;
        float f0 = sWc[0 * 576 + tap * 64 + ppos], f1 = sWc[1 * 576 + tap * 64 + ppos];
        float f2 = sWc[2 * 576 + tap * 64 + ppos], f3 = sWc[3 * 576 + tap * 64 + ppos];
        const uint* c0 = (const uint*)&g[0];
        const uint* c1 = (const uint*)&g[1];
        const uint* c2 = (const uint*)&g[2];
        const uint* c3 = (const uint*)&g[3];
        uint r[4];
#pragma unroll
        for (int j = 0; j < 4; ++j) {
            float ev = f0 * blo(c0[j]) + f1 * blo(c1[j]) + f2 * blo(c2[j]) + f3 * blo(c3[j]);
            float ov = f0 * bhi(c0[j]) + f1 * bhi(c1[j]) + f2 * bhi(c2[j]) + f3 * bhi(c3[j]);
            r[j] = pack2(ev, ov);
        }
        uint4 gg = {r[0], r[1], r[2], r[3]};
        *(uint4*)&lAb[ppos * 64 + ((pc8 ^ (ppos & 7)) * 8)] = gg;
    };
    // consumer: this wave's 16 channels: r = nh*128 + wvc*16 + mrow
    auto loadB = [&](int sl, bf16x8 (&br)[2]) {
        int tap = sl >> 2, cb = sl & 3;
        int r = nh * 128 + wvc * 16 + mrow;
        const ushort* base = bt + (size_t)r * KD + tap * 256 + cb * 64 + quad * 8;
        br[0] = *(const bf16x8*)(base);
        br[1] = *(const bf16x8*)(base + 32);
    };
    auto mfma_pass = [&](int bi, const bf16x8 (&br)[2]) {
#pragma unroll
        for (int kb = 0; kb < 2; ++kb) {
            bf16x8 af[4];
#pragma unroll
            for (int m = 0; m < 4; ++m) {
                int r = m * 16 + mrow;
                af[m] = *(const bf16x8*)&lA[bi * 4096 + r * 64 + (((kb * 4 + quad) ^ (r & 7)) * 8)];
            }
#pragma unroll
            for (int m = 0; m < 4; ++m)
                acc[m] = __builtin_amdgcn_mfma_f32_16x16x32_bf16(af[m], br[kb], acc[m], 0, 0, 0);
        }
    };

    uint4 gA[4];
    bf16x8 brA[2], brB[2];
    if (producer) {
        issue_gathers(0, gA);
        finish(0, &lA[0], gA);
        issue_gathers(1, gA);
        finish(1, &lA[4096], gA);
        asm volatile("s_waitcnt lgkmcnt(0)" ::: "memory");
    } else {
        loadB(0, brA);
        loadB(1, brB);
    }
    __builtin_amdgcn_s_barrier();
    __builtin_amdgcn_sched_barrier(0);

    for (int s = 0; s < 36; s += 2) {
        if (producer) {
            if (s + 2 < 36) {
                issue_gathers(s + 2, gA);
                finish(s + 2, &lA[((s + 2) & 3) * 4096], gA);
                issue_gathers(s + 3, gA);
                finish(s + 3, &lA[((s + 3) & 3) * 4096], gA);
                asm volatile("s_waitcnt lgkmcnt(0)" ::: "memory");
            }
        } else {
            __builtin_amdgcn_s_setprio(1);
            mfma_pass(s & 3, brA);
            mfma_pass((s + 1) & 3, brB);
            __builtin_amdgcn_s_setprio(0);
            if (s + 2 < 36) loadB(s + 2, brA);
            if (s + 3 < 36) loadB(s + 3, brB);
        }
        __builtin_amdgcn_s_barrier();
        __builtin_amdgcn_sched_barrier(0);
    }

    // ---- epilogue (consumers only): store + BN stats ----
    if (!producer) {
        int o = nh * 128 + wvc * 16 + mrow;
        float ss = 0.f, qq = 0.f;
#pragma unroll
        for (int m = 0; m < 4; ++m) {
            int pos = m * 16 + quad * 4;
            f32x4 v = acc[m];
            *(f32x4*)(out + ((size_t)(b * 256 + o)) * HW + h * 64 + pos) = v;
            ss += v.x + v.y + v.z + v.w;
            qq += v.x * v.x + v.y * v.y + v.z * v.z + v.w * v.w;
        }
        ss += __shfl_xor(ss, 16); ss += __shfl_xor(ss, 32);
        qq += __shfl_xor(qq, 16); qq += __shfl_xor(qq, 32);
        if (quad == 0) {
            atomicAdd(&stats[o], ss);
            atomicAdd(&stats[512 + o], qq);
        }
    }
}

// ---- BN finalize folded into apply: o is block-uniform ((bid>>2)&255) ----
__global__ __launch_bounds__(256) void bn_apply(float* __restrict__ out,
                                                const float* __restrict__ stats,
                                                const float* __restrict__ gamma,
                                                const float* __restrict__ beta) {
    int bid = blockIdx.x;                        // 4096
    int o = (bid >> 2) & 255;
    float S = stats[o], S2 = stats[512 + o];
    float mu  = S * (1.f / 16384.f);
    float var = S2 * (1.f / 16384.f) - mu * mu;
    float sc  = gamma[o] * rsqrtf(var + 1e-5f);
    float be  = beta[o];
    int idx4 = bid * 256 + threadIdx.x;          // 1,048,576 float4s
    float4 v = ((const float4*)out)[idx4];
    v.x = fmaxf((v.x - mu) * sc + be, 0.f);
    v.y = fmaxf((v.y - mu) * sc + be, 0.f);
    v.z = fmaxf((v.z - mu) * sc + be, 0.f);
    v.w = fmaxf((v.w - mu) * sc + be, 0.f);
    ((float4*)out)[idx4] = v;
}

extern "C" void kernel_launch(void* const* d_in, const int* in_sizes, int n_in,
                              void* d_out, int out_size, void* d_ws, size_t ws_size,
                              hipStream_t stream) {
    const float* x     = (const float*)d_in[0];
    const float* w_off = (const float*)d_in[1];
    const float* b_off = (const float*)d_in[2];
    const float* w_def = (const float*)d_in[3];
    const float* gamma = (const float*)d_in[4];
    const float* beta  = (const float*)d_in[5];
    float* out = (float*)d_out;

    char* ws = (char*)d_ws;
    uint*   x2t   = (uint*)ws;                          // 8,388,608 B
    ushort* bt    = (ushort*)(ws + 8388608);            // 1,179,648 B
    ushort* bt0   = (ushort*)(ws + 9568256);            // 147,456 B
    float*  stats = (float*)(ws + 9715712);             // 4,096 B

    prep_all  <<<3617, 256, 0, stream>>>(x, w_def, w_off, x2t, bt, bt0, stats);
    fused_main<<<512, 1024, 0, stream>>>(x2t, bt, bt0, b_off, out, stats);
    bn_apply  <<<4096, 256, 0, stream>>>(out, stats, gamma, beta);
}

// Round 16
// 167.775 us; speedup vs baseline: 1.2004x; 1.2004x over previous
//
#include <hip/hip_runtime.h>
#include <hip/hip_bf16.h>

typedef unsigned int  uint;
typedef unsigned short ushort;
typedef short bf16x8 __attribute__((ext_vector_type(8)));
typedef float f32x4  __attribute__((ext_vector_type(4)));

#define HW   4096
#define KD   2304   // 9 taps * 256 c

__device__ __forceinline__ void load_lds16(const void* g, void* l) {
    __builtin_amdgcn_global_load_lds((const __attribute__((address_space(1))) void*)g,
                                     (__attribute__((address_space(3))) void*)l, 16, 0, 0);
}
__device__ __forceinline__ float blo(uint u) { return __uint_as_float(u << 16); }
__device__ __forceinline__ float bhi(uint u) { return __uint_as_float(u & 0xffff0000u); }
__device__ __forceinline__ uint pack2(float e, float o) {
    __hip_bfloat16 he = __float2bfloat16(e), ho = __float2bfloat16(o);
    return (uint)(*(ushort*)&he) | ((uint)(*(ushort*)&ho) << 16);
}

// ---- merged prep: x->x2t transpose | w_def->bt | w_off->bt0 | stats zero ----
__global__ __launch_bounds__(256) void prep_all(const float* __restrict__ x,
                                                const float* __restrict__ w_def,
                                                const float* __restrict__ w_off,
                                                uint* __restrict__ x2t,
                                                ushort* __restrict__ bt,
                                                ushort* __restrict__ bt0,
                                                float* __restrict__ stats) {
    __shared__ uint tl[32][65];
    int bid = blockIdx.x;
    int t = threadIdx.x;
    if (bid < 1024) {
        int ab  = bid & 63;
        int cpb = (bid >> 6) & 3;
        int b   = bid >> 8;
#pragma unroll
        for (int i = 0; i < 8; ++i) {
            int idx = i * 256 + t;
            int cp = idx >> 6, a = idx & 63;
            const float* p = x + ((size_t)(b * 256 + (cpb * 32 + cp) * 2)) * HW + ab * 64 + a;
            tl[cp][a] = pack2(p[0], p[HW]);
        }
        __syncthreads();
#pragma unroll
        for (int i = 0; i < 8; ++i) {
            int idx = i * 256 + t;
            int a = idx >> 5, cp = idx & 31;
            x2t[((size_t)b * 4096 + ab * 64 + a) * 128 + cpb * 32 + cp] = tl[cp][a];
        }
    } else if (bid < 3328) {
        int idx = (bid - 1024) * 256 + t;          // 589,824
        int c   = idx & 255;
        int tap = (idx >> 8) % 9;
        int o   = idx / KD;
        __hip_bfloat16 h = __float2bfloat16(w_def[(o * 256 + c) * 9 + tap]);
        bt[idx] = *(ushort*)&h;
    } else if (bid < 3616) {
        int idx = (bid - 3328) * 256 + t;          // 73,728
        int c   = idx & 255;
        int tap = (idx >> 8) % 9;
        int j   = idx / KD;
        float v = (j < 18) ? w_off[(j * 256 + c) * 9 + tap] : 0.f;
        __hip_bfloat16 h = __float2bfloat16(v);
        bt0[idx] = *(ushort*)&h;
    } else {
        float4 z = {0.f, 0.f, 0.f, 0.f};
        ((float4*)stats)[t] = z;                   // 256 float4 = 4096 B
    }
}

// ---- MEGA kernel, 512-THREAD blocks, N-split, 2 independent blocks/CU ----
// R15 mapped the trade: 16-wave blocks get registers XOR occupancy. 512-thread
// blocks get both: 2 blocks/CU x 8 waves = 4 waves/EU (128-reg budget, the
// proven no-spill regime) with TWO independent barrier domains per CU — the
// convoy-stall hypothesis' lever. Waves 0-3 producers (16 positions each via
// 2 sub-groups), waves 4-7 consumers (32 channels each of this block's
// nh-half). Phase A = original 512-thread gemm_off (proven) -> sOff in LDS.
__global__ __attribute__((amdgpu_waves_per_eu(4, 4))) __launch_bounds__(512)
void fused_main(const uint* __restrict__ x2t,
                const ushort* __restrict__ bt,
                const ushort* __restrict__ bt0,
                const float* __restrict__ b_off,
                float* __restrict__ out,
                float* __restrict__ stats) {
    int id = blockIdx.x;                      // 512 blocks
    int nh = id & 1;                          // N-half: channels nh*128..+127
    int bid2 = id >> 1;                       // 0..255 (b,h) tile
    int xcd = bid2 & 7;
    int b = xcd >> 1, h = (xcd & 1) * 32 + (bid2 >> 3);
    int t = threadIdx.x;
    int wv = t >> 6, lane = t & 63;
    int mrow = lane & 15, quad = lane >> 4;
    bool producer = (wv < 4);
    int pc8  = lane & 7;                      // producer 16B chunk (4 cp)
    int wvc  = wv - 4;                        // consumer wave 0..3

    __shared__ __align__(16) char smem[66048];
    uint*   lX   = (uint*)smem;               // phase A: 24576 B
    ushort* lB0  = (ushort*)(smem + 24576);   // phase A: 36864 B
    float*  sOff = (float*)(smem + 61440);    // 18*64*4 = 4608 B
    int*    sAc  = (int*)smem;                // main: 9216 B
    float*  sWc  = (float*)(smem + 9216);     // 9216 B
    ushort* lA   = (ushort*)(smem + 18432);   // 4 * 8192 B

    // ================= phase A: offset conv (original 512-thread gemm_off) ====
    {
        f32x4 accO = {0.f, 0.f, 0.f, 0.f};
        int mq = wv & 3, nn = wv >> 2;
        for (int cb = 0; cb < 4; ++cb) {
#pragma unroll
            for (int s = 0; s < 3; ++s) {      // 24 lX phases over 8 waves
                int q   = s * 8 + wv;
                int dy  = q >> 3;
                int y   = h + dy - 1;
                int sub = q & 7;
                int wl  = sub * 8 + (lane >> 3);
                int cps = ((lane & 7) ^ ((lane >> 3) & 7)) * 4;
                if ((unsigned)y < 64u) {
                    const uint* src = x2t + ((size_t)(b * 4096 + y * 64 + wl)) * 128 + cb * 32 + cps;
                    load_lds16(src, &lX[q * 256]);
                } else {
                    uint4 z = {0u, 0u, 0u, 0u};
                    *(uint4*)&lX[q * 256 + lane * 4] = z;
                }
            }
#pragma unroll
            for (int s = 0; s < 5; ++s) {      // 36 lB0 phases over 8 waves
                int q = s * 8 + wv;
                if (q < 36) {
                    int e = q * 512 + lane * 8;
                    int o  = e / 576;
                    int r  = e - o * 576;
                    int chp = r >> 3;
                    int ch  = chp ^ (o & 7);
                    int tap = ch >> 3, k8 = ch & 7;
                    const ushort* src = bt0 + (size_t)o * KD + tap * 256 + cb * 64 + k8 * 8;
                    load_lds16(src, &lB0[q * 512]);
                }
            }
            __syncthreads();
#pragma unroll
            for (int tap = 0; tap < 9; ++tap) {
                int dy = tap / 3, dx = tap % 3;
                int xx = mq * 16 + mrow + dx - 1;
                bool vx = (unsigned)xx < 64u;
                int xc = min(max(xx, 0), 63);
#pragma unroll
                for (int kb = 0; kb < 2; ++kb) {
                    int cp0 = kb * 16 + quad * 4;
                    uint4 ad = {0u, 0u, 0u, 0u};
                    if (vx) ad = *(const uint4*)&lX[dy * 2048 + xc * 32 + (cp0 ^ ((xc & 7) * 4))];
                    bf16x8 af = *(bf16x8*)&ad;
                    int o = nn * 16 + mrow;
                    int chs = (tap * 8 + (((kb * 4 + quad)) ^ (o & 7)));
                    bf16x8 bfr = *(const bf16x8*)&lB0[o * 576 + chs * 8];
                    accO = __builtin_amdgcn_mfma_f32_16x16x32_bf16(af, bfr, accO, 0, 0, 0);
                }
            }
            __syncthreads();
        }
        {
            int o = (wv >> 2) * 16 + mrow;
            if (o < 18) {
                float bias = b_off[o];
                int wpos = (wv & 3) * 16 + quad * 4;
                sOff[o * 64 + wpos + 0] = accO.x + bias;
                sOff[o * 64 + wpos + 1] = accO.y + bias;
                sOff[o * 64 + wpos + 2] = accO.z + bias;
                sOff[o * 64 + wpos + 3] = accO.w + bias;
            }
        }
        __syncthreads();
    }

    // ================= coord phase =================
    for (int i = t; i < 576; i += 512) {
        int tap = i >> 6, ww = i & 63;
        float oy = sOff[(2 * tap) * 64 + ww];
        float ox = sOff[(2 * tap + 1) * 64 + ww];
        float py = oy + (float)(tap / 3 + h - 1);
        float px = ox + (float)(tap % 3 + ww - 1);
        float y0f = floorf(py), x0f = floorf(px);
        float wy1 = py - y0f, wx1 = px - x0f;
        float wy0 = 1.f - wy1, wx0 = 1.f - wx1;
        bool vy0 = (y0f >= 0.f) && (y0f <= 63.f);
        bool vy1 = (y0f >= -1.f) && (y0f <= 62.f);
        bool vx0 = (x0f >= 0.f) && (x0f <= 63.f);
        bool vx1 = (x0f >= -1.f) && (x0f <= 62.f);
        int iy0 = min(max((int)y0f, 0), 63),  iy1 = min(max((int)y0f + 1, 0), 63);
        int ix0 = min(max((int)x0f, 0), 63),  ix1 = min(max((int)x0f + 1, 0), 63);
        sAc[0 * 576 + tap * 64 + ww] = iy0 * 64 + ix0;
        sAc[1 * 576 + tap * 64 + ww] = iy0 * 64 + ix1;
        sAc[2 * 576 + tap * 64 + ww] = iy1 * 64 + ix0;
        sAc[3 * 576 + tap * 64 + ww] = iy1 * 64 + ix1;
        sWc[0 * 576 + tap * 64 + ww] = wy0 * wx0 * (float)(vy0 && vx0);
        sWc[1 * 576 + tap * 64 + ww] = wy0 * wx1 * (float)(vy0 && vx1);
        sWc[2 * 576 + tap * 64 + ww] = wy1 * wx0 * (float)(vy1 && vx0);
        sWc[3 * 576 + tap * 64 + ww] = wy1 * wx1 * (float)(vy1 && vx1);
    }
    __syncthreads();

    // ================= main P/C loop =================
    f32x4 acc[4][2];
#pragma unroll
    for (int m = 0; m < 4; ++m)
#pragma unroll
        for (int n = 0; n < 2; ++n) acc[m][n] = {0.f, 0.f, 0.f, 0.f};

    const uint* xb = x2t + (size_t)b * 4096 * 128;

    // producer: position group h2 of this wave: ppos = wv*16 + h2*8 + lane>>3
    auto issue_gathers = [&](int sl, int h2, uint4 (&g)[4]) {
        int tap = sl >> 2, cb = sl & 3;
        int ppos = (wv << 4) + (h2 << 3) + (lane >> 3);
        const uint* xp = xb + cb * 32 + pc8 * 4;
        g[0] = *(const uint4*)(xp + (size_t)sAc[0 * 576 + tap * 64 + ppos] * 128);
        g[1] = *(const uint4*)(xp + (size_t)sAc[1 * 576 + tap * 64 + ppos] * 128);
        g[2] = *(const uint4*)(xp + (size_t)sAc[2 * 576 + tap * 64 + ppos] * 128);
        g[3] = *(const uint4*)(xp + (size_t)sAc[3 * 576 + tap * 64 + ppos] * 128);
    };
    auto finish = [&](int sl, int h2, ushort* lAb, const uint4 (&g)[4]) {
        int tap = sl >> 2;
        int ppos = (wv << 4) + (h2 << 3) + (lane >> 3);
        float f0 = sWc[0 * 576 + tap * 64 + ppos], f1 = sWc[1 * 576 + tap * 64 + ppos];
        float f2 = sWc[2 * 576 + tap * 64 + ppos], f3 = sWc[3 * 576 + tap * 64 + ppos];
        const uint* c0 = (const uint*)&g[0];
        const uint* c1 = (const uint*)&g[1];
        const uint* c2 = (const uint*)&g[2];
        const uint* c3 = (const uint*)&g[3];
        uint r[4];
#pragma unroll
        for (int j = 0; j < 4; ++j) {
            float ev = f0 * blo(c0[j]) + f1 * blo(c1[j]) + f2 * blo(c2[j]) + f3 * blo(c3[j]);
            float ov = f0 * bhi(c0[j]) + f1 * bhi(c1[j]) + f2 * bhi(c2[j]) + f3 * bhi(c3[j]);
            r[j] = pack2(ev, ov);
        }
        uint4 gg = {r[0], r[1], r[2], r[3]};
        *(uint4*)&lAb[ppos * 64 + ((pc8 ^ (ppos & 7)) * 8)] = gg;
    };
    auto stage_slice = [&](int sl, ushort* lAb) {
        uint4 g0[4], g1[4];
        issue_gathers(sl, 0, g0);
        issue_gathers(sl, 1, g1);
        finish(sl, 0, lAb, g0);
        finish(sl, 1, lAb, g1);
    };
    // consumer: rows r = nh*128 + wvc*32 + n*16 + mrow
    auto loadB = [&](int sl, bf16x8 (&br)[4]) {
        int tap = sl >> 2, cb = sl & 3;
        const ushort* base = bt + (size_t)(nh * 128) * KD + tap * 256 + cb * 64 + quad * 8;
#pragma unroll
        for (int kb = 0; kb < 2; ++kb)
#pragma unroll
            for (int n = 0; n < 2; ++n) {
                int r = wvc * 32 + n * 16 + mrow;
                br[kb * 2 + n] = *(const bf16x8*)(base + (size_t)r * KD + kb * 32);
            }
    };
    auto mfma_pass = [&](int bi, const bf16x8 (&br)[4]) {
#pragma unroll
        for (int kb = 0; kb < 2; ++kb) {
            bf16x8 af[4];
#pragma unroll
            for (int m = 0; m < 4; ++m) {
                int r = m * 16 + mrow;
                af[m] = *(const bf16x8*)&lA[bi * 4096 + r * 64 + (((kb * 4 + quad) ^ (r & 7)) * 8)];
            }
#pragma unroll
            for (int n = 0; n < 2; ++n)
#pragma unroll
                for (int m = 0; m < 4; ++m)
                    acc[m][n] = __builtin_amdgcn_mfma_f32_16x16x32_bf16(af[m], br[kb * 2 + n], acc[m][n], 0, 0, 0);
        }
    };

    bf16x8 brA[4], brB[4];
    if (producer) {
        stage_slice(0, &lA[0]);
        stage_slice(1, &lA[4096]);
        asm volatile("s_waitcnt lgkmcnt(0)" ::: "memory");
    } else {
        loadB(0, brA);
        loadB(1, brB);
    }
    __builtin_amdgcn_s_barrier();
    __builtin_amdgcn_sched_barrier(0);

    for (int s = 0; s < 36; s += 2) {
        if (producer) {
            if (s + 2 < 36) {
                stage_slice(s + 2, &lA[((s + 2) & 3) * 4096]);
                stage_slice(s + 3, &lA[((s + 3) & 3) * 4096]);
                asm volatile("s_waitcnt lgkmcnt(0)" ::: "memory");
            }
        } else {
            __builtin_amdgcn_s_setprio(1);
            mfma_pass(s & 3, brA);
            mfma_pass((s + 1) & 3, brB);
            __builtin_amdgcn_s_setprio(0);
            if (s + 2 < 36) loadB(s + 2, brA);
            if (s + 3 < 36) loadB(s + 3, brB);
        }
        __builtin_amdgcn_s_barrier();
        __builtin_amdgcn_sched_barrier(0);
    }

    // ---- epilogue (consumers only): store + BN stats ----
    if (!producer) {
#pragma unroll
        for (int n = 0; n < 2; ++n) {
            int o = nh * 128 + wvc * 32 + n * 16 + mrow;
            float ss = 0.f, qq = 0.f;
#pragma unroll
            for (int m = 0; m < 4; ++m) {
                int pos = m * 16 + quad * 4;
                f32x4 v = acc[m][n];
                *(f32x4*)(out + ((size_t)(b * 256 + o)) * HW + h * 64 + pos) = v;
                ss += v.x + v.y + v.z + v.w;
                qq += v.x * v.x + v.y * v.y + v.z * v.z + v.w * v.w;
            }
            ss += __shfl_xor(ss, 16); ss += __shfl_xor(ss, 32);
            qq += __shfl_xor(qq, 16); qq += __shfl_xor(qq, 32);
            if (quad == 0) {
                atomicAdd(&stats[o], ss);
                atomicAdd(&stats[512 + o], qq);
            }
        }
    }
}

// ---- BN finalize folded into apply: o is block-uniform ((bid>>2)&255) ----
__global__ __launch_bounds__(256) void bn_apply(float* __restrict__ out,
                                                const float* __restrict__ stats,
                                                const float* __restrict__ gamma,
                                                const float* __restrict__ beta) {
    int bid = blockIdx.x;                        // 4096
    int o = (bid >> 2) & 255;
    float S = stats[o], S2 = stats[512 + o];
    float mu  = S * (1.f / 16384.f);
    float var = S2 * (1.f / 16384.f) - mu * mu;
    float sc  = gamma[o] * rsqrtf(var + 1e-5f);
    float be  = beta[o];
    int idx4 = bid * 256 + threadIdx.x;          // 1,048,576 float4s
    float4 v = ((const float4*)out)[idx4];
    v.x = fmaxf((v.x - mu) * sc + be, 0.f);
    v.y = fmaxf((v.y - mu) * sc + be, 0.f);
    v.z = fmaxf((v.z - mu) * sc + be, 0.f);
    v.w = fmaxf((v.w - mu) * sc + be, 0.f);
    ((float4*)out)[idx4] = v;
}

extern "C" void kernel_launch(void* const* d_in, const int* in_sizes, int n_in,
                              void* d_out, int out_size, void* d_ws, size_t ws_size,
                              hipStream_t stream) {
    const float* x     = (const float*)d_in[0];
    const float* w_off = (const float*)d_in[1];
    const float* b_off = (const float*)d_in[2];
    const float* w_def = (const float*)d_in[3];
    const float* gamma = (const float*)d_in[4];
    const float* beta  = (const float*)d_in[5];
    float* out = (float*)d_out;

    char* ws = (char*)d_ws;
    uint*   x2t   = (uint*)ws;                          // 8,388,608 B
    ushort* bt    = (ushort*)(ws + 8388608);            // 1,179,648 B
    ushort* bt0   = (ushort*)(ws + 9568256);            // 147,456 B
    float*  stats = (float*)(ws + 9715712);             // 4,096 B

    prep_all  <<<3617, 256, 0, stream>>>(x, w_def, w_off, x2t, bt, bt0, stats);
    fused_main<<<512, 512, 0, stream>>>(x2t, bt, bt0, b_off, out, stats);
    bn_apply  <<<4096, 256, 0, stream>>>(out, stats, gamma, beta);
}

// Round 17
// 145.604 us; speedup vs baseline: 1.3831x; 1.1523x over previous
//
#include <hip/hip_runtime.h>
#include <hip/hip_bf16.h>

typedef unsigned int  uint;
typedef unsigned short ushort;
typedef short bf16x8 __attribute__((ext_vector_type(8)));
typedef float f32x4  __attribute__((ext_vector_type(4)));

#define HW   4096
#define KD   2304   // 9 taps * 256 c

__device__ __forceinline__ void load_lds16(const void* g, void* l) {
    __builtin_amdgcn_global_load_lds((const __attribute__((address_space(1))) void*)g,
                                     (__attribute__((address_space(3))) void*)l, 16, 0, 0);
}
__device__ __forceinline__ float blo(uint u) { return __uint_as_float(u << 16); }
__device__ __forceinline__ float bhi(uint u) { return __uint_as_float(u & 0xffff0000u); }
__device__ __forceinline__ uint pack2(float e, float o) {
    __hip_bfloat16 he = __float2bfloat16(e), ho = __float2bfloat16(o);
    return (uint)(*(ushort*)&he) | ((uint)(*(ushort*)&ho) << 16);
}

// ---- merged prep: x->x2t transpose | w_def->bt | w_off->bt0 | stats zero ----
__global__ __launch_bounds__(256) void prep_all(const float* __restrict__ x,
                                                const float* __restrict__ w_def,
                                                const float* __restrict__ w_off,
                                                uint* __restrict__ x2t,
                                                ushort* __restrict__ bt,
                                                ushort* __restrict__ bt0,
                                                float* __restrict__ stats) {
    __shared__ uint tl[32][65];
    int bid = blockIdx.x;
    int t = threadIdx.x;
    if (bid < 1024) {
        int ab  = bid & 63;
        int cpb = (bid >> 6) & 3;
        int b   = bid >> 8;
#pragma unroll
        for (int i = 0; i < 8; ++i) {
            int idx = i * 256 + t;
            int cp = idx >> 6, a = idx & 63;
            const float* p = x + ((size_t)(b * 256 + (cpb * 32 + cp) * 2)) * HW + ab * 64 + a;
            tl[cp][a] = pack2(p[0], p[HW]);
        }
        __syncthreads();
#pragma unroll
        for (int i = 0; i < 8; ++i) {
            int idx = i * 256 + t;
            int a = idx >> 5, cp = idx & 31;
            x2t[((size_t)b * 4096 + ab * 64 + a) * 128 + cpb * 32 + cp] = tl[cp][a];
        }
    } else if (bid < 3328) {
        int idx = (bid - 1024) * 256 + t;          // 589,824
        int c   = idx & 255;
        int tap = (idx >> 8) % 9;
        int o   = idx / KD;
        __hip_bfloat16 h = __float2bfloat16(w_def[(o * 256 + c) * 9 + tap]);
        bt[idx] = *(ushort*)&h;
    } else if (bid < 3616) {
        int idx = (bid - 3328) * 256 + t;          // 73,728
        int c   = idx & 255;
        int tap = (idx >> 8) % 9;
        int j   = idx / KD;
        float v = (j < 18) ? w_off[(j * 256 + c) * 9 + tap] : 0.f;
        __hip_bfloat16 h = __float2bfloat16(v);
        bt0[idx] = *(ushort*)&h;
    } else {
        float4 z = {0.f, 0.f, 0.f, 0.f};
        ((float4*)stats)[t] = z;                   // 256 float4 = 4096 B
    }
}

// ---- MEGA kernel: offset conv (phase A) + gather/interp + main GEMM + BN stats ----
// Phase A = old gemm_off fused in: same (b,h) block mapping, result kept in LDS
// (sOff 18x64 f32) instead of a 2 MB global round-trip; staging spread over all
// 16 waves. Then coord phase reads sOff; main P/C loop: producers (waves 0-7)
// gather+interp+stage lA; consumers (waves 8-15) B-from-global + MFMA.
// LDS union: phaseA {lX 24K @0, lB0 36K @24K, sOff 4.5K @60K} | main {sAc 9K @0,
// sWc 9K @9K, lA 32K @18K} — phase A buffers dead before main writes them.
__global__ __attribute__((amdgpu_waves_per_eu(4, 4))) __launch_bounds__(1024)
void fused_main(const uint* __restrict__ x2t,
                const ushort* __restrict__ bt,
                const ushort* __restrict__ bt0,
                const float* __restrict__ b_off,
                float* __restrict__ out,
                float* __restrict__ stats) {
    int id = blockIdx.x;                      // 256 blocks
    int xcd = id & 7;
    int b = xcd >> 1, h = (xcd & 1) * 32 + (id >> 3);
    int t = threadIdx.x;
    int wv = t >> 6, lane = t & 63;
    int mrow = lane & 15, quad = lane >> 4;
    bool producer = (wv < 8);
    int ppos = ((wv & 7) << 3) + (lane >> 3); // producer position 0..63
    int pc8  = lane & 7;                      // producer 16B chunk (4 cp)
    int wvc  = wv - 8;                        // consumer wave 0..7

    __shared__ __align__(16) char smem[66048];
    uint*   lX   = (uint*)smem;               // phase A: 24576 B
    ushort* lB0  = (ushort*)(smem + 24576);   // phase A: 36864 B
    float*  sOff = (float*)(smem + 61440);    // 18*64*4 = 4608 B
    int*    sAc  = (int*)smem;                // main: 9216 B
    float*  sWc  = (float*)(smem + 9216);     // 9216 B
    ushort* lA   = (ushort*)(smem + 18432);   // 4 * 8192 B

    // ================= phase A: offset conv =================
    {
        f32x4 accO = {0.f, 0.f, 0.f, 0.f};
        int mq = wv & 3, nn = (wv >> 2) & 1;
        for (int cb = 0; cb < 4; ++cb) {
#pragma unroll
            for (int s = 0; s < 2; ++s) {             // 24 lX phases / 16 waves
                int q = s * 16 + wv;
                if (q < 24) {
                    int dy  = q >> 3;
                    int y   = h + dy - 1;
                    int sub = q & 7;
                    int wl  = sub * 8 + (lane >> 3);
                    int cps = ((lane & 7) ^ ((lane >> 3) & 7)) * 4;
                    if ((unsigned)y < 64u) {
                        const uint* src = x2t + ((size_t)(b * 4096 + y * 64 + wl)) * 128 + cb * 32 + cps;
                        load_lds16(src, &lX[q * 256]);
                    } else {
                        uint4 z = {0u, 0u, 0u, 0u};
                        *(uint4*)&lX[q * 256 + lane * 4] = z;
                    }
                }
            }
#pragma unroll
            for (int s = 0; s < 3; ++s) {             // 36 lB0 phases / 16 waves
                int q = s * 16 + wv;
                if (q < 36) {
                    int e = q * 512 + lane * 8;
                    int o  = e / 576;
                    int r  = e - o * 576;
                    int chp = r >> 3;
                    int ch  = chp ^ (o & 7);
                    int tap = ch >> 3, k8 = ch & 7;
                    const ushort* src = bt0 + (size_t)o * KD + tap * 256 + cb * 64 + k8 * 8;
                    load_lds16(src, &lB0[q * 512]);
                }
            }
            __syncthreads();
            if (producer) {
#pragma unroll
                for (int tap = 0; tap < 9; ++tap) {
                    int dy = tap / 3, dx = tap % 3;
                    int xx = mq * 16 + mrow + dx - 1;
                    bool vx = (unsigned)xx < 64u;
                    int xc = min(max(xx, 0), 63);
#pragma unroll
                    for (int kb = 0; kb < 2; ++kb) {
                        int cp0 = kb * 16 + quad * 4;
                        uint4 ad = {0u, 0u, 0u, 0u};
                        if (vx) ad = *(const uint4*)&lX[dy * 2048 + xc * 32 + (cp0 ^ ((xc & 7) * 4))];
                        bf16x8 af = *(bf16x8*)&ad;
                        int o = nn * 16 + mrow;
                        int chs = (tap * 8 + (((kb * 4 + quad)) ^ (o & 7)));
                        bf16x8 bfr = *(const bf16x8*)&lB0[o * 576 + chs * 8];
                        accO = __builtin_amdgcn_mfma_f32_16x16x32_bf16(af, bfr, accO, 0, 0, 0);
                    }
                }
            }
            __syncthreads();
        }
        if (producer) {
            int o = ((wv >> 2) & 1) * 16 + mrow;
            if (o < 18) {
                float bias = b_off[o];
                int wpos = (wv & 3) * 16 + quad * 4;
                sOff[o * 64 + wpos + 0] = accO.x + bias;
                sOff[o * 64 + wpos + 1] = accO.y + bias;
                sOff[o * 64 + wpos + 2] = accO.z + bias;
                sOff[o * 64 + wpos + 3] = accO.w + bias;
            }
        }
        __syncthreads();
    }

    // ================= coord phase =================
    for (int i = t; i < 576; i += 1024) {
        int tap = i >> 6, ww = i & 63;
        float oy = sOff[(2 * tap) * 64 + ww];
        float ox = sOff[(2 * tap + 1) * 64 + ww];
        float py = oy + (float)(tap / 3 + h - 1);
        float px = ox + (float)(tap % 3 + ww - 1);
        float y0f = floorf(py), x0f = floorf(px);
        float wy1 = py - y0f, wx1 = px - x0f;
        float wy0 = 1.f - wy1, wx0 = 1.f - wx1;
        bool vy0 = (y0f >= 0.f) && (y0f <= 63.f);
        bool vy1 = (y0f >= -1.f) && (y0f <= 62.f);
        bool vx0 = (x0f >= 0.f) && (x0f <= 63.f);
        bool vx1 = (x0f >= -1.f) && (x0f <= 62.f);
        int iy0 = min(max((int)y0f, 0), 63),  iy1 = min(max((int)y0f + 1, 0), 63);
        int ix0 = min(max((int)x0f, 0), 63),  ix1 = min(max((int)x0f + 1, 0), 63);
        sAc[0 * 576 + tap * 64 + ww] = iy0 * 64 + ix0;
        sAc[1 * 576 + tap * 64 + ww] = iy0 * 64 + ix1;
        sAc[2 * 576 + tap * 64 + ww] = iy1 * 64 + ix0;
        sAc[3 * 576 + tap * 64 + ww] = iy1 * 64 + ix1;
        sWc[0 * 576 + tap * 64 + ww] = wy0 * wx0 * (float)(vy0 && vx0);
        sWc[1 * 576 + tap * 64 + ww] = wy0 * wx1 * (float)(vy0 && vx1);
        sWc[2 * 576 + tap * 64 + ww] = wy1 * wx0 * (float)(vy1 && vx0);
        sWc[3 * 576 + tap * 64 + ww] = wy1 * wx1 * (float)(vy1 && vx1);
    }
    __syncthreads();

    // ================= main P/C loop =================
    f32x4 acc[4][2];
#pragma unroll
    for (int m = 0; m < 4; ++m)
#pragma unroll
        for (int n = 0; n < 2; ++n) acc[m][n] = {0.f, 0.f, 0.f, 0.f};

    const uint* xb = x2t + (size_t)b * 4096 * 128;

    auto issue_gathers = [&](int sl, uint4 (&g)[4]) {
        int tap = sl >> 2, cb = sl & 3;
        const uint* xp = xb + cb * 32 + pc8 * 4;
        g[0] = *(const uint4*)(xp + (size_t)sAc[0 * 576 + tap * 64 + ppos] * 128);
        g[1] = *(const uint4*)(xp + (size_t)sAc[1 * 576 + tap * 64 + ppos] * 128);
        g[2] = *(const uint4*)(xp + (size_t)sAc[2 * 576 + tap * 64 + ppos] * 128);
        g[3] = *(const uint4*)(xp + (size_t)sAc[3 * 576 + tap * 64 + ppos] * 128);
    };
    auto finish = [&](int sl, ushort* lAb, const uint4 (&g)[4]) {
        int tap = sl >> 2;
        float f0 = sWc[0 * 576 + tap * 64 + ppos], f1 = sWc[1 * 576 + tap * 64 + ppos];
        float f2 = sWc[2 * 576 + tap * 64 + ppos], f3 = sWc[3 * 576 + tap * 64 + ppos];
        const uint* c0 = (const uint*)&g[0];
        const uint* c1 = (const uint*)&g[1];
        const uint* c2 = (const uint*)&g[2];
        const uint* c3 = (const uint*)&g[3];
        uint r[4];
#pragma unroll
        for (int j = 0; j < 4; ++j) {
            float ev = f0 * blo(c0[j]) + f1 * blo(c1[j]) + f2 * blo(c2[j]) + f3 * blo(c3[j]);
            float ov = f0 * bhi(c0[j]) + f1 * bhi(c1[j]) + f2 * bhi(c2[j]) + f3 * bhi(c3[j]);
            r[j] = pack2(ev, ov);
        }
        uint4 gg = {r[0], r[1], r[2], r[3]};
        *(uint4*)&lAb[ppos * 64 + ((pc8 ^ (ppos & 7)) * 8)] = gg;
    };
    auto loadB = [&](int sl, bf16x8 (&br)[4]) {
        int tap = sl >> 2, cb = sl & 3;
        const ushort* base = bt + tap * 256 + cb * 64 + quad * 8;
#pragma unroll
        for (int kb = 0; kb < 2; ++kb)
#pragma unroll
            for (int n = 0; n < 2; ++n) {
                int r = wvc * 32 + n * 16 + mrow;
                br[kb * 2 + n] = *(const bf16x8*)(base + (size_t)r * KD + kb * 32);
            }
    };
    auto mfma_pass = [&](int bi, const bf16x8 (&br)[4]) {
#pragma unroll
        for (int kb = 0; kb < 2; ++kb) {
            bf16x8 af[4];
#pragma unroll
            for (int m = 0; m < 4; ++m) {
                int r = m * 16 + mrow;
                af[m] = *(const bf16x8*)&lA[bi * 4096 + r * 64 + (((kb * 4 + quad) ^ (r & 7)) * 8)];
            }
#pragma unroll
            for (int n = 0; n < 2; ++n)
#pragma unroll
                for (int m = 0; m < 4; ++m)
                    acc[m][n] = __builtin_amdgcn_mfma_f32_16x16x32_bf16(af[m], br[kb * 2 + n], acc[m][n], 0, 0, 0);
        }
    };

    uint4 gA[4];
    bf16x8 brA[4], brB[4];
    if (producer) {
        issue_gathers(0, gA);
        finish(0, &lA[0], gA);
        issue_gathers(1, gA);
        finish(1, &lA[4096], gA);
        asm volatile("s_waitcnt lgkmcnt(0)" ::: "memory");
    } else {
        loadB(0, brA);
        loadB(1, brB);
    }
    __builtin_amdgcn_s_barrier();
    __builtin_amdgcn_sched_barrier(0);

    for (int s = 0; s < 36; s += 2) {
        if (producer) {
            if (s + 2 < 36) {
                issue_gathers(s + 2, gA);
                finish(s + 2, &lA[((s + 2) & 3) * 4096], gA);
                issue_gathers(s + 3, gA);
                finish(s + 3, &lA[((s + 3) & 3) * 4096], gA);
                asm volatile("s_waitcnt lgkmcnt(0)" ::: "memory");
            }
        } else {
            __builtin_amdgcn_s_setprio(1);
            mfma_pass(s & 3, brA);
            mfma_pass((s + 1) & 3, brB);
            __builtin_amdgcn_s_setprio(0);
            if (s + 2 < 36) loadB(s + 2, brA);
            if (s + 3 < 36) loadB(s + 3, brB);
        }
        __builtin_amdgcn_s_barrier();
        __builtin_amdgcn_sched_barrier(0);
    }

    // ---- epilogue (consumers only): store + BN stats ----
    if (!producer) {
#pragma unroll
        for (int n = 0; n < 2; ++n) {
            int o = wvc * 32 + n * 16 + mrow;
            float ss = 0.f, qq = 0.f;
#pragma unroll
            for (int m = 0; m < 4; ++m) {
                int pos = m * 16 + quad * 4;
                f32x4 v = acc[m][n];
                *(f32x4*)(out + ((size_t)(b * 256 + o)) * HW + h * 64 + pos) = v;
                ss += v.x + v.y + v.z + v.w;
                qq += v.x * v.x + v.y * v.y + v.z * v.z + v.w * v.w;
            }
            ss += __shfl_xor(ss, 16); ss += __shfl_xor(ss, 32);
            qq += __shfl_xor(qq, 16); qq += __shfl_xor(qq, 32);
            if (quad == 0) {
                atomicAdd(&stats[o], ss);
                atomicAdd(&stats[512 + o], qq);
            }
        }
    }
}

// ---- BN finalize folded into apply: o is block-uniform ((bid>>2)&255) ----
__global__ __launch_bounds__(256) void bn_apply(float* __restrict__ out,
                                                const float* __restrict__ stats,
                                                const float* __restrict__ gamma,
                                                const float* __restrict__ beta) {
    int bid = blockIdx.x;                        // 4096
    int o = (bid >> 2) & 255;
    float S = stats[o], S2 = stats[512 + o];
    float mu  = S * (1.f / 16384.f);
    float var = S2 * (1.f / 16384.f) - mu * mu;
    float sc  = gamma[o] * rsqrtf(var + 1e-5f);
    float be  = beta[o];
    int idx4 = bid * 256 + threadIdx.x;          // 1,048,576 float4s
    float4 v = ((const float4*)out)[idx4];
    v.x = fmaxf((v.x - mu) * sc + be, 0.f);
    v.y = fmaxf((v.y - mu) * sc + be, 0.f);
    v.z = fmaxf((v.z - mu) * sc + be, 0.f);
    v.w = fmaxf((v.w - mu) * sc + be, 0.f);
    ((float4*)out)[idx4] = v;
}

extern "C" void kernel_launch(void* const* d_in, const int* in_sizes, int n_in,
                              void* d_out, int out_size, void* d_ws, size_t ws_size,
                              hipStream_t stream) {
    const float* x     = (const float*)d_in[0];
    const float* w_off = (const float*)d_in[1];
    const float* b_off = (const float*)d_in[2];
    const float* w_def = (const float*)d_in[3];
    const float* gamma = (const float*)d_in[4];
    const float* beta  = (const float*)d_in[5];
    float* out = (float*)d_out;

    char* ws = (char*)d_ws;
    uint*   x2t   = (uint*)ws;                          // 8,388,608 B
    ushort* bt    = (ushort*)(ws + 8388608);            // 1,179,648 B
    ushort* bt0   = (ushort*)(ws + 9568256);            // 147,456 B
    float*  stats = (float*)(ws + 9715712);             // 4,096 B

    prep_all  <<<3617, 256, 0, stream>>>(x, w_def, w_off, x2t, bt, bt0, stats);
    fused_main<<<256, 1024, 0, stream>>>(x2t, bt, bt0, b_off, out, stats);
    bn_apply  <<<4096, 256, 0, stream>>>(out, stats, gamma, beta);
}